// Round 15
// baseline (122.114 us; speedup 1.0000x reference)
//
#include <hip/hip_runtime.h>
#include <stdint.h>

#define NMOD 8
#define NLAY 4
#define NN   32
#define NB   16
#define HW   16384
#define BHW  262144
#define NE   256
#define NT   256

// ---- workspace layout (u32 word offsets) ----
// ex[B*HW] | in[B*HW] | pair[NE] | off[NN+1]
#define EXW 0
#define INW (NB * HW)
#define PRW (2 * NB * HW)
#define OFW (2 * NB * HW + NE)
#define WS_NEED_BYTES ((size_t)(2 * NB * HW + NE + NN + 1) * 4)

__device__ __forceinline__ float lo_bf(uint32_t u) {
    union { uint32_t u32; float f; } v; v.u32 = u << 16; return v.f;
}
__device__ __forceinline__ float hi_bf(uint32_t u) {
    union { uint32_t u32; float f; } v; v.u32 = u & 0xffff0000u; return v.f;
}
__device__ __forceinline__ uint32_t f2bf(float f) {
    union { float ff; uint32_t u; } v; v.ff = f;
    uint32_t u = v.u;
    u += 0x7fffu + ((u >> 16) & 1u);   // round-to-nearest-even
    return u >> 16;
}

// R6: two-kernel split via d_ws. R9: wave-split setup. R11: no-LDS main,
// scalar CSR, 4-wide, 1024 blocks, bounds(256,4) -- best 117.4.
// R12/R13 (CLOSED): more blocks/CU regress. R14: pair-prefetch neutral ->
// conn-load chain is the binding hop.
// R15: re-balance block to 4 batches x 2 dsts (grid stays 1024, 4 blk/CU):
// serial conn groups/thread 8 -> 4, conn loads/output 4 -> 2, each conn
// load feeds 16 FMA. Codes/output 0.5 -> 1.0 (L2/L3-resident, cheap).
// Est ~96 VGPR live < 128 cap. Spill alarm: WRITE > ~40 MB or VGPR==32.

// ================= setup kernel: 1024 blocks x 256 (R9 verbatim) =========
extern "C" __global__ void __launch_bounds__(NT, 4) scs_setup_kernel(
    const void* __restrict__ d_spikes,  // [N,B,H,W]  bf16 or f32
    const void* __restrict__ d_mask,    // [N,H,W]    bf16 or f32
    const void* __restrict__ d_scale,   // [2]
    const int*  __restrict__ conn_src,  // [E]
    const int*  __restrict__ conn_dst,  // [E]
    uint32_t*   __restrict__ d_ws)
{
    __shared__ uint32_t l_part[8 * NT];   // [word][wave][lane], 8 KB
    const int tid = threadIdx.x;
    const bool is_f32 = (*(const uint32_t*)d_scale) == 0x3F800000u;

    // ---- CSR build (block 0 only): group connections by dst ----
    if (blockIdx.x == 0) {
        __shared__ int s_off[NN + 1];
        __shared__ int s_cnt[NN];
        __shared__ int s_pair[NE];
        const int my_s = conn_src[tid];             // NE == NT
        const int my_d = conn_dst[tid];
        if (tid < NN) s_cnt[tid] = 0;
        __syncthreads();
        atomicAdd(&s_cnt[my_d], 1);
        __syncthreads();
        if (tid < NN) {
            int v = s_cnt[tid];
#pragma unroll
            for (int d = 1; d < NN; d <<= 1) {
                int t = __shfl_up(v, d);
                if (tid >= d) v += t;
            }
            s_off[tid + 1] = v;
            if (tid == 0) s_off[0] = 0;
            s_cnt[tid] = 0;
        }
        __syncthreads();
        {
            int pos = s_off[my_d] + atomicAdd(&s_cnt[my_d], 1);
            s_pair[pos] = (my_s << 8) | tid;
        }
        __syncthreads();
        d_ws[PRW + tid] = (uint32_t)s_pair[tid];
        if (tid <= NN) d_ws[OFW + tid] = (uint32_t)s_off[tid];
    }

    const int w   = tid >> 6;                 // wave 0..3
    const int l   = tid & 63;                 // lane = quad slot
    const int n00 = w * 8;                    // first node of this wave
    const int Q   = blockIdx.x * 64 + l;      // global quad 0..65535
    const int b   = Q >> 12;                  // HW/4 = 4096
    const int hwq = Q & (HW / 4 - 1);

    uint32_t ex0 = 0, in0 = 0, ex1 = 0, in1 = 0;
    uint32_t ex2 = 0, in2 = 0, ex3 = 0, in3 = 0;
    if (is_f32) {
        const float4* sp = (const float4*)d_spikes;
        const float4* mk = (const float4*)d_mask;
        float4 s[8], m[8];
#pragma unroll
        for (int j = 0; j < 8; ++j) {
            s[j] = sp[(n00 + j) * (BHW / 4) + b * (HW / 4) + hwq];
            m[j] = mk[(n00 + j) * (HW / 4) + hwq];
        }
#pragma unroll
        for (int j = 0; j < 8; ++j) {
            const uint32_t bit = 1u << (n00 + j);
            const float p0 = s[j].x * m[j].x;   // in {0, 1, -0.5} exactly
            const float p1 = s[j].y * m[j].y;
            const float p2 = s[j].z * m[j].z;
            const float p3 = s[j].w * m[j].w;
            if (p0 > 0.f) ex0 |= bit;  if (p0 < 0.f) in0 |= bit;
            if (p1 > 0.f) ex1 |= bit;  if (p1 < 0.f) in1 |= bit;
            if (p2 > 0.f) ex2 |= bit;  if (p2 < 0.f) in2 |= bit;
            if (p3 > 0.f) ex3 |= bit;  if (p3 < 0.f) in3 |= bit;
        }
    } else {
        const uint2* sp = (const uint2*)d_spikes;
        const uint2* mk = (const uint2*)d_mask;
        uint2 su[8], mu[8];
#pragma unroll
        for (int j = 0; j < 8; ++j) {
            su[j] = sp[(n00 + j) * (BHW / 4) + b * (HW / 4) + hwq];
            mu[j] = mk[(n00 + j) * (HW / 4) + hwq];
        }
#pragma unroll
        for (int j = 0; j < 8; ++j) {
            const uint32_t bit = 1u << (n00 + j);
            const float p0 = lo_bf(su[j].x) * lo_bf(mu[j].x);
            const float p1 = hi_bf(su[j].x) * hi_bf(mu[j].x);
            const float p2 = lo_bf(su[j].y) * lo_bf(mu[j].y);
            const float p3 = hi_bf(su[j].y) * hi_bf(mu[j].y);
            if (p0 > 0.f) ex0 |= bit;  if (p0 < 0.f) in0 |= bit;
            if (p1 > 0.f) ex1 |= bit;  if (p1 < 0.f) in1 |= bit;
            if (p2 > 0.f) ex2 |= bit;  if (p2 < 0.f) in2 |= bit;
            if (p3 > 0.f) ex3 |= bit;  if (p3 < 0.f) in3 |= bit;
        }
    }
    // partials -> LDS [word][wave][lane]; lanes hit distinct banks
    l_part[0 * NT + w * 64 + l] = ex0;  l_part[1 * NT + w * 64 + l] = ex1;
    l_part[2 * NT + w * 64 + l] = ex2;  l_part[3 * NT + w * 64 + l] = ex3;
    l_part[4 * NT + w * 64 + l] = in0;  l_part[5 * NT + w * 64 + l] = in1;
    l_part[6 * NT + w * 64 + l] = in2;  l_part[7 * NT + w * 64 + l] = in3;
    __syncthreads();
    // combine: threads 0..127; thread = (h, l): h=0 ex words, h=1 in words
    if (tid < 128) {
        const int h  = tid >> 6;        // 0 -> ex, 1 -> in
        const int ll = tid & 63;
        const int wb = h * 4;
        uint4 r;
        r.x = l_part[(wb + 0) * NT + 0 * 64 + ll] | l_part[(wb + 0) * NT + 1 * 64 + ll]
            | l_part[(wb + 0) * NT + 2 * 64 + ll] | l_part[(wb + 0) * NT + 3 * 64 + ll];
        r.y = l_part[(wb + 1) * NT + 0 * 64 + ll] | l_part[(wb + 1) * NT + 1 * 64 + ll]
            | l_part[(wb + 1) * NT + 2 * 64 + ll] | l_part[(wb + 1) * NT + 3 * 64 + ll];
        r.z = l_part[(wb + 2) * NT + 0 * 64 + ll] | l_part[(wb + 2) * NT + 1 * 64 + ll]
            | l_part[(wb + 2) * NT + 2 * 64 + ll] | l_part[(wb + 2) * NT + 3 * 64 + ll];
        r.w = l_part[(wb + 3) * NT + 0 * 64 + ll] | l_part[(wb + 3) * NT + 1 * 64 + ll]
            | l_part[(wb + 3) * NT + 2 * 64 + ll] | l_part[(wb + 3) * NT + 3 * 64 + ll];
        ((uint4*)(d_ws + (h == 0 ? EXW : INW)))[blockIdx.x * 64 + ll] = r;
    }
}

// ================= main kernel: 1024 blocks x 256, NO LDS ================
// block = (chunk 0..15, bq 0..3, gg 0..15); 4 batches x 2 dst rows.
// Both dsts are in module gg>>1.
extern "C" __global__ void __launch_bounds__(NT, 4) scs_main_kernel(
    const void* __restrict__ d_connw,   // [E,H,W]  bf16 or f32
    const void* __restrict__ d_scale,   // [2]
    const uint32_t* __restrict__ ws,
    void* __restrict__ d_outp)          // [N,B,H,W]
{
    const int tid   = threadIdx.x;
    // XCD swizzle: idx&7 == XCD id; each XCD sees chunks {c, c+8}.
    const int idx   = blockIdx.x;                        // 0..1023
    const int chunk = (idx & 7) + 8 * ((idx >> 9) & 1);  // 0..15
    const int mid   = (idx >> 3) & 63;
    const int bq    = mid & 3;                           // 0..3
    const int gg    = mid >> 2;                          // 0..15 dst pair
    const int bbase = bq * 4;                            // batches bbase..+3
    const int n0    = gg * 2;                            // 2 dsts, module gg>>1
    const int hw0   = chunk * (4 * NT) + tid * 4;
    const int hwq   = hw0 >> 2;
    int spq[4];
#pragma unroll
    for (int bb = 0; bb < 4; ++bb)
        spq[bb] = ((bbase + bb) * HW + hw0) >> 2;

    const bool is_f32 = (*(const uint32_t*)d_scale) == 0x3F800000u;

    // ---- scalar CSR bounds for this block's 2 dsts (uniform -> s_load) ----
    int off[3];
#pragma unroll
    for (int i = 0; i <= 2; ++i)
        off[i] = __builtin_amdgcn_readfirstlane((int)ws[OFW + n0 + i]);

    // ---- per-element modulated codes, 4 batches (vector loads) ----
    uint32_t exw[4][4], inw[4][4];
#pragma unroll
    for (int bb = 0; bb < 4; ++bb) {
        const uint4 e = *(const uint4*)(ws + EXW + (size_t)((bbase + bb) * HW + hw0));
        const uint4 n = *(const uint4*)(ws + INW + (size_t)((bbase + bb) * HW + hw0));
        exw[bb][0] = e.x; exw[bb][1] = e.y; exw[bb][2] = e.z; exw[bb][3] = e.w;
        inw[bb][0] = n.x; inw[bb][1] = n.y; inw[bb][2] = n.z; inw[bb][3] = n.w;
    }

    float w1, w2;
    if (is_f32) {
        const float* sc = (const float*)d_scale;
        w1 = sc[0]; w2 = sc[1];
    } else {
        const uint16_t* sc = (const uint16_t*)d_scale;
        w1 = lo_bf((uint32_t)sc[0]); w2 = lo_bf((uint32_t)sc[1]);
    }

    // ---- multi-scale grid from popcounts (spike bit = ex|in) ----
    float g[4][4];   // [batch][elem]
    {
        const int m = gg >> 1;
#pragma unroll
        for (int bb = 0; bb < 4; ++bb) {
#pragma unroll
            for (int e = 0; e < 4; ++e) {
                const uint32_t sw = exw[bb][e] | inw[bb][e];
                int t = 0, u = 0;
                if (m >= 1)       t += __popc((sw >> (4 * (m - 1))) & 0xFu);
                if (m + 1 < NMOD) t += __popc((sw >> (4 * (m + 1))) & 0xFu);
                if (m >= 2)       u += __popc((sw >> (4 * (m - 2))) & 0xFu);
                if (m + 2 < NMOD) u += __popc((sw >> (4 * (m + 2))) & 0xFu);
                g[bb][e] = ((float)t * w1 + (float)u * w2) * 0.25f; // mean
            }
        }
    }

    // decode: v = (ex>>s & 1) - 0.5*(in>>s & 1), s in SGPR

    // ---- per-dst accumulate: 2 dst rows x 4 batches, 4-wide ----
    if (is_f32) {
        const float4* cw  = (const float4*)d_connw;
        float4*       out = (float4*)d_outp;
#pragma unroll
        for (int i = 0; i < 2; ++i) {
            const int n = n0 + i;
            float acc[4][4];
#pragma unroll
            for (int bb = 0; bb < 4; ++bb)
#pragma unroll
                for (int e = 0; e < 4; ++e) acc[bb][e] = g[bb][e];
            const int beg = off[i];
            const int end = off[i + 1];
            int k = beg;
            for (; k + 4 <= end; k += 4) {
                int p[4];
#pragma unroll
                for (int j = 0; j < 4; ++j)
                    p[j] = __builtin_amdgcn_readfirstlane((int)ws[PRW + k + j]);
                float4 wv[4];
#pragma unroll
                for (int j = 0; j < 4; ++j)
                    wv[j] = cw[(p[j] & 0xff) * (HW / 4) + hwq];
#pragma unroll
                for (int j = 0; j < 4; ++j) {
                    const int s = p[j] >> 8;
#pragma unroll
                    for (int bb = 0; bb < 4; ++bb) {
                        const float v0 = (float)((exw[bb][0] >> s) & 1u) - 0.5f * (float)((inw[bb][0] >> s) & 1u);
                        const float v1 = (float)((exw[bb][1] >> s) & 1u) - 0.5f * (float)((inw[bb][1] >> s) & 1u);
                        const float v2 = (float)((exw[bb][2] >> s) & 1u) - 0.5f * (float)((inw[bb][2] >> s) & 1u);
                        const float v3 = (float)((exw[bb][3] >> s) & 1u) - 0.5f * (float)((inw[bb][3] >> s) & 1u);
                        acc[bb][0] = fmaf(v0, wv[j].x, acc[bb][0]);
                        acc[bb][1] = fmaf(v1, wv[j].y, acc[bb][1]);
                        acc[bb][2] = fmaf(v2, wv[j].z, acc[bb][2]);
                        acc[bb][3] = fmaf(v3, wv[j].w, acc[bb][3]);
                    }
                }
            }
            for (; k < end; ++k) {
                const int pk = __builtin_amdgcn_readfirstlane((int)ws[PRW + k]);
                float4 wv = cw[(pk & 0xff) * (HW / 4) + hwq];
                const int s = pk >> 8;
#pragma unroll
                for (int bb = 0; bb < 4; ++bb) {
                    const float v0 = (float)((exw[bb][0] >> s) & 1u) - 0.5f * (float)((inw[bb][0] >> s) & 1u);
                    const float v1 = (float)((exw[bb][1] >> s) & 1u) - 0.5f * (float)((inw[bb][1] >> s) & 1u);
                    const float v2 = (float)((exw[bb][2] >> s) & 1u) - 0.5f * (float)((inw[bb][2] >> s) & 1u);
                    const float v3 = (float)((exw[bb][3] >> s) & 1u) - 0.5f * (float)((inw[bb][3] >> s) & 1u);
                    acc[bb][0] = fmaf(v0, wv.x, acc[bb][0]);
                    acc[bb][1] = fmaf(v1, wv.y, acc[bb][1]);
                    acc[bb][2] = fmaf(v2, wv.z, acc[bb][2]);
                    acc[bb][3] = fmaf(v3, wv.w, acc[bb][3]);
                }
            }
#pragma unroll
            for (int bb = 0; bb < 4; ++bb) {
                float4 o;
                o.x = acc[bb][0]; o.y = acc[bb][1];
                o.z = acc[bb][2]; o.w = acc[bb][3];
                out[n * (BHW / 4) + spq[bb]] = o;
            }
        }
    } else {
        const uint2* cw  = (const uint2*)d_connw;
        uint2*       out = (uint2*)d_outp;
#pragma unroll
        for (int i = 0; i < 2; ++i) {
            const int n = n0 + i;
            float acc[4][4];
#pragma unroll
            for (int bb = 0; bb < 4; ++bb)
#pragma unroll
                for (int e = 0; e < 4; ++e) acc[bb][e] = g[bb][e];
            const int beg = off[i];
            const int end = off[i + 1];
            int k = beg;
            for (; k + 4 <= end; k += 4) {
                int p[4];
#pragma unroll
                for (int j = 0; j < 4; ++j)
                    p[j] = __builtin_amdgcn_readfirstlane((int)ws[PRW + k + j]);
                uint2 wv[4];
#pragma unroll
                for (int j = 0; j < 4; ++j)
                    wv[j] = cw[(p[j] & 0xff) * (HW / 4) + hwq];
#pragma unroll
                for (int j = 0; j < 4; ++j) {
                    const int s = p[j] >> 8;
                    const float wa = lo_bf(wv[j].x), wb = hi_bf(wv[j].x);
                    const float wc = lo_bf(wv[j].y), wd = hi_bf(wv[j].y);
#pragma unroll
                    for (int bb = 0; bb < 4; ++bb) {
                        const float v0 = (float)((exw[bb][0] >> s) & 1u) - 0.5f * (float)((inw[bb][0] >> s) & 1u);
                        const float v1 = (float)((exw[bb][1] >> s) & 1u) - 0.5f * (float)((inw[bb][1] >> s) & 1u);
                        const float v2 = (float)((exw[bb][2] >> s) & 1u) - 0.5f * (float)((inw[bb][2] >> s) & 1u);
                        const float v3 = (float)((exw[bb][3] >> s) & 1u) - 0.5f * (float)((inw[bb][3] >> s) & 1u);
                        acc[bb][0] = fmaf(v0, wa, acc[bb][0]);
                        acc[bb][1] = fmaf(v1, wb, acc[bb][1]);
                        acc[bb][2] = fmaf(v2, wc, acc[bb][2]);
                        acc[bb][3] = fmaf(v3, wd, acc[bb][3]);
                    }
                }
            }
            for (; k < end; ++k) {
                const int pk = __builtin_amdgcn_readfirstlane((int)ws[PRW + k]);
                uint2 wv = cw[(pk & 0xff) * (HW / 4) + hwq];
                const int s = pk >> 8;
                const float wa = lo_bf(wv.x), wb = hi_bf(wv.x);
                const float wc = lo_bf(wv.y), wd = hi_bf(wv.y);
#pragma unroll
                for (int bb = 0; bb < 4; ++bb) {
                    const float v0 = (float)((exw[bb][0] >> s) & 1u) - 0.5f * (float)((inw[bb][0] >> s) & 1u);
                    const float v1 = (float)((exw[bb][1] >> s) & 1u) - 0.5f * (float)((inw[bb][1] >> s) & 1u);
                    const float v2 = (float)((exw[bb][2] >> s) & 1u) - 0.5f * (float)((inw[bb][2] >> s) & 1u);
                    const float v3 = (float)((exw[bb][3] >> s) & 1u) - 0.5f * (float)((inw[bb][3] >> s) & 1u);
                    acc[bb][0] = fmaf(v0, wa, acc[bb][0]);
                    acc[bb][1] = fmaf(v1, wb, acc[bb][1]);
                    acc[bb][2] = fmaf(v2, wc, acc[bb][2]);
                    acc[bb][3] = fmaf(v3, wd, acc[bb][3]);
                }
            }
#pragma unroll
            for (int bb = 0; bb < 4; ++bb) {
                uint2 o;
                o.x = f2bf(acc[bb][0]) | (f2bf(acc[bb][1]) << 16);
                o.y = f2bf(acc[bb][2]) | (f2bf(acc[bb][3]) << 16);
                out[n * (BHW / 4) + spq[bb]] = o;
            }
        }
    }
}

// ================= fallback: R4 verbatim (ws too small) =================
struct ScsSmem {
    int off[NN + 1];
    int cnt[NN];
    int pair[NE];
};

extern "C" __global__ void __launch_bounds__(NT, 4) scs_fallback_kernel(
    const void* __restrict__ d_spikes, const void* __restrict__ d_mask,
    const void* __restrict__ d_connw,  const void* __restrict__ d_scale,
    const int*  __restrict__ conn_src, const int* __restrict__ conn_dst,
    void*       __restrict__ d_outp)
{
    __shared__ ScsSmem sm;
    const int tid   = threadIdx.x;
    const int idx   = blockIdx.x;
    const int chunk = (idx & 7) + 8 * ((idx >> 9) & 1);
    const int mid   = (idx >> 3) & 63;
    const int b     = mid & 15;
    const int ng    = mid >> 4;
    const int n0    = ng * (NN / 4);
    const int hw0   = chunk * (4 * NT) + tid * 4;
    const int hwq   = hw0 >> 2;
    const int spq   = (b * HW + hw0) >> 2;
    const bool is_f32 = (*(const uint32_t*)d_scale) == 0x3F800000u;

    const int my_s = conn_src[tid];
    const int my_d = conn_dst[tid];
    if (tid < NN) sm.cnt[tid] = 0;
    __syncthreads();
    atomicAdd(&sm.cnt[my_d], 1);
    __syncthreads();
    if (tid < NN) {
        int v = sm.cnt[tid];
#pragma unroll
        for (int d = 1; d < NN; d <<= 1) {
            int t = __shfl_up(v, d);
            if (tid >= d) v += t;
        }
        sm.off[tid + 1] = v;
        if (tid == 0) sm.off[0] = 0;
        sm.cnt[tid] = 0;
    }
    __syncthreads();
    {
        int pos = sm.off[my_d] + atomicAdd(&sm.cnt[my_d], 1);
        sm.pair[pos] = (my_s << 8) | tid;
    }

    uint32_t ex0 = 0, in0 = 0, ex1 = 0, in1 = 0;
    uint32_t ex2 = 0, in2 = 0, ex3 = 0, in3 = 0;
    float av0[NMOD], av1[NMOD], av2[NMOD], av3[NMOD];
#pragma unroll
    for (int m = 0; m < NMOD; ++m) { av0[m] = 0.f; av1[m] = 0.f; av2[m] = 0.f; av3[m] = 0.f; }

    float w1, w2;
    if (is_f32) {
        const float* sc = (const float*)d_scale;
        w1 = sc[0]; w2 = sc[1];
        const float4* sp = (const float4*)d_spikes;
        const float4* mk = (const float4*)d_mask;
#pragma unroll
        for (int g = 0; g < NN / 4; ++g) {
            float4 s[4], m[4];
#pragma unroll
            for (int j = 0; j < 4; ++j) {
                s[j] = sp[(g * 4 + j) * (BHW / 4) + spq];
                m[j] = mk[(g * 4 + j) * (HW / 4) + hwq];
            }
#pragma unroll
            for (int j = 0; j < 4; ++j) {
                const int n = g * 4 + j;
                const uint32_t bit = 1u << n;
                const float p0 = s[j].x * m[j].x;
                const float p1 = s[j].y * m[j].y;
                const float p2 = s[j].z * m[j].z;
                const float p3 = s[j].w * m[j].w;
                if (p0 > 0.f) ex0 |= bit;  if (p0 < 0.f) in0 |= bit;
                if (p1 > 0.f) ex1 |= bit;  if (p1 < 0.f) in1 |= bit;
                if (p2 > 0.f) ex2 |= bit;  if (p2 < 0.f) in2 |= bit;
                if (p3 > 0.f) ex3 |= bit;  if (p3 < 0.f) in3 |= bit;
                av0[n >> 2] += s[j].x;
                av1[n >> 2] += s[j].y;
                av2[n >> 2] += s[j].z;
                av3[n >> 2] += s[j].w;
            }
        }
    } else {
        const uint16_t* sc = (const uint16_t*)d_scale;
        w1 = lo_bf((uint32_t)sc[0]); w2 = lo_bf((uint32_t)sc[1]);
        const uint2* sp = (const uint2*)d_spikes;
        const uint2* mk = (const uint2*)d_mask;
#pragma unroll
        for (int g = 0; g < NN / 4; ++g) {
            uint2 su[4], mu[4];
#pragma unroll
            for (int j = 0; j < 4; ++j) {
                su[j] = sp[(g * 4 + j) * (BHW / 4) + spq];
                mu[j] = mk[(g * 4 + j) * (HW / 4) + hwq];
            }
#pragma unroll
            for (int j = 0; j < 4; ++j) {
                const int n = g * 4 + j;
                const uint32_t bit = 1u << n;
                const float s0 = lo_bf(su[j].x), s1 = hi_bf(su[j].x);
                const float s2 = lo_bf(su[j].y), s3 = hi_bf(su[j].y);
                const float p0 = s0 * lo_bf(mu[j].x);
                const float p1 = s1 * hi_bf(mu[j].x);
                const float p2 = s2 * lo_bf(mu[j].y);
                const float p3 = s3 * hi_bf(mu[j].y);
                if (p0 > 0.f) ex0 |= bit;  if (p0 < 0.f) in0 |= bit;
                if (p1 > 0.f) ex1 |= bit;  if (p1 < 0.f) in1 |= bit;
                if (p2 > 0.f) ex2 |= bit;  if (p2 < 0.f) in2 |= bit;
                if (p3 > 0.f) ex3 |= bit;  if (p3 < 0.f) in3 |= bit;
                av0[n >> 2] += s0;
                av1[n >> 2] += s1;
                av2[n >> 2] += s2;
                av3[n >> 2] += s3;
            }
        }
    }

    float gA0, gA1, gA2, gA3, gB0, gB1, gB2, gB3;
    {
        float g0[NMOD], g1[NMOD], g2[NMOD], g3[NMOD];
#pragma unroll
        for (int m = 0; m < NMOD; ++m) {
            float t0 = 0.f, t1 = 0.f, t2 = 0.f, t3 = 0.f;
            float u0 = 0.f, u1 = 0.f, u2 = 0.f, u3 = 0.f;
            if (m >= 1)       { t0 += av0[m-1]; t1 += av1[m-1]; t2 += av2[m-1]; t3 += av3[m-1]; }
            if (m + 1 < NMOD) { t0 += av0[m+1]; t1 += av1[m+1]; t2 += av2[m+1]; t3 += av3[m+1]; }
            if (m >= 2)       { u0 += av0[m-2]; u1 += av1[m-2]; u2 += av2[m-2]; u3 += av3[m-2]; }
            if (m + 2 < NMOD) { u0 += av0[m+2]; u1 += av1[m+2]; u2 += av2[m+2]; u3 += av3[m+2]; }
            g0[m] = (t0 * w1 + u0 * w2) * 0.25f;
            g1[m] = (t1 * w1 + u1 * w2) * 0.25f;
            g2[m] = (t2 * w1 + u2 * w2) * 0.25f;
            g3[m] = (t3 * w1 + u3 * w2) * 0.25f;
        }
        if      (ng == 0) { gA0=g0[0]; gA1=g1[0]; gA2=g2[0]; gA3=g3[0]; gB0=g0[1]; gB1=g1[1]; gB2=g2[1]; gB3=g3[1]; }
        else if (ng == 1) { gA0=g0[2]; gA1=g1[2]; gA2=g2[2]; gA3=g3[2]; gB0=g0[3]; gB1=g1[3]; gB2=g2[3]; gB3=g3[3]; }
        else if (ng == 2) { gA0=g0[4]; gA1=g1[4]; gA2=g2[4]; gA3=g3[4]; gB0=g0[5]; gB1=g1[5]; gB2=g2[5]; gB3=g3[5]; }
        else              { gA0=g0[6]; gA1=g1[6]; gA2=g2[6]; gA3=g3[6]; gB0=g0[7]; gB1=g1[7]; gB2=g2[7]; gB3=g3[7]; }
    }

    __syncthreads();

    if (is_f32) {
        const float4* cw  = (const float4*)d_connw;
        float4*       out = (float4*)d_outp;
#pragma unroll
        for (int i = 0; i < NN / 4; ++i) {
            const int n = n0 + i;
            float a0 = (i < 4) ? gA0 : gB0;
            float a1 = (i < 4) ? gA1 : gB1;
            float a2 = (i < 4) ? gA2 : gB2;
            float a3 = (i < 4) ? gA3 : gB3;
            const int beg = __builtin_amdgcn_readfirstlane(sm.off[n]);
            const int end = __builtin_amdgcn_readfirstlane(sm.off[n + 1]);
            int k = beg;
            for (; k + 4 <= end; k += 4) {
                int p[4];
#pragma unroll
                for (int j = 0; j < 4; ++j)
                    p[j] = __builtin_amdgcn_readfirstlane(sm.pair[k + j]);
                float4 wv[4];
#pragma unroll
                for (int j = 0; j < 4; ++j)
                    wv[j] = cw[(p[j] & 0xff) * (HW / 4) + hwq];
#pragma unroll
                for (int j = 0; j < 4; ++j) {
                    const int s = p[j] >> 8;
                    const float v0 = (float)((ex0 >> s) & 1u) - 0.5f * (float)((in0 >> s) & 1u);
                    const float v1 = (float)((ex1 >> s) & 1u) - 0.5f * (float)((in1 >> s) & 1u);
                    const float v2 = (float)((ex2 >> s) & 1u) - 0.5f * (float)((in2 >> s) & 1u);
                    const float v3 = (float)((ex3 >> s) & 1u) - 0.5f * (float)((in3 >> s) & 1u);
                    a0 = fmaf(v0, wv[j].x, a0);
                    a1 = fmaf(v1, wv[j].y, a1);
                    a2 = fmaf(v2, wv[j].z, a2);
                    a3 = fmaf(v3, wv[j].w, a3);
                }
            }
            for (; k < end; ++k) {
                const int pk = __builtin_amdgcn_readfirstlane(sm.pair[k]);
                float4 wv = cw[(pk & 0xff) * (HW / 4) + hwq];
                const int s = pk >> 8;
                const float v0 = (float)((ex0 >> s) & 1u) - 0.5f * (float)((in0 >> s) & 1u);
                const float v1 = (float)((ex1 >> s) & 1u) - 0.5f * (float)((in1 >> s) & 1u);
                const float v2 = (float)((ex2 >> s) & 1u) - 0.5f * (float)((in2 >> s) & 1u);
                const float v3 = (float)((ex3 >> s) & 1u) - 0.5f * (float)((in3 >> s) & 1u);
                a0 = fmaf(v0, wv.x, a0);
                a1 = fmaf(v1, wv.y, a1);
                a2 = fmaf(v2, wv.z, a2);
                a3 = fmaf(v3, wv.w, a3);
            }
            float4 o; o.x = a0; o.y = a1; o.z = a2; o.w = a3;
            out[n * (BHW / 4) + spq] = o;
        }
    } else {
        const uint2* cw  = (const uint2*)d_connw;
        uint2*       out = (uint2*)d_outp;
#pragma unroll
        for (int i = 0; i < NN / 4; ++i) {
            const int n = n0 + i;
            float a0 = (i < 4) ? gA0 : gB0;
            float a1 = (i < 4) ? gA1 : gB1;
            float a2 = (i < 4) ? gA2 : gB2;
            float a3 = (i < 4) ? gA3 : gB3;
            const int beg = __builtin_amdgcn_readfirstlane(sm.off[n]);
            const int end = __builtin_amdgcn_readfirstlane(sm.off[n + 1]);
            int k = beg;
            for (; k + 4 <= end; k += 4) {
                int p[4];
#pragma unroll
                for (int j = 0; j < 4; ++j)
                    p[j] = __builtin_amdgcn_readfirstlane(sm.pair[k + j]);
                uint2 wv[4];
#pragma unroll
                for (int j = 0; j < 4; ++j)
                    wv[j] = cw[(p[j] & 0xff) * (HW / 4) + hwq];
#pragma unroll
                for (int j = 0; j < 4; ++j) {
                    const int s = p[j] >> 8;
                    const float v0 = (float)((ex0 >> s) & 1u) - 0.5f * (float)((in0 >> s) & 1u);
                    const float v1 = (float)((ex1 >> s) & 1u) - 0.5f * (float)((in1 >> s) & 1u);
                    const float v2 = (float)((ex2 >> s) & 1u) - 0.5f * (float)((in2 >> s) & 1u);
                    const float v3 = (float)((ex3 >> s) & 1u) - 0.5f * (float)((in3 >> s) & 1u);
                    a0 = fmaf(v0, lo_bf(wv[j].x), a0);
                    a1 = fmaf(v1, hi_bf(wv[j].x), a1);
                    a2 = fmaf(v2, lo_bf(wv[j].y), a2);
                    a3 = fmaf(v3, hi_bf(wv[j].y), a3);
                }
            }
            for (; k < end; ++k) {
                const int pk = __builtin_amdgcn_readfirstlane(sm.pair[k]);
                uint2 wv = cw[(pk & 0xff) * (HW / 4) + hwq];
                const int s = pk >> 8;
                const float v0 = (float)((ex0 >> s) & 1u) - 0.5f * (float)((in0 >> s) & 1u);
                const float v1 = (float)((ex1 >> s) & 1u) - 0.5f * (float)((in1 >> s) & 1u);
                const float v2 = (float)((ex2 >> s) & 1u) - 0.5f * (float)((in2 >> s) & 1u);
                const float v3 = (float)((ex3 >> s) & 1u) - 0.5f * (float)((in3 >> s) & 1u);
                a0 = fmaf(v0, lo_bf(wv.x), a0);
                a1 = fmaf(v1, hi_bf(wv.x), a1);
                a2 = fmaf(v2, lo_bf(wv.y), a2);
                a3 = fmaf(v3, hi_bf(wv.y), a3);
            }
            uint2 o;
            o.x = f2bf(a0) | (f2bf(a1) << 16);
            o.y = f2bf(a2) | (f2bf(a3) << 16);
            out[n * (BHW / 4) + spq] = o;
        }
    }
}

extern "C" void kernel_launch(void* const* d_in, const int* in_sizes, int n_in,
                              void* d_out, int out_size, void* d_ws, size_t ws_size,
                              hipStream_t stream) {
    if (d_ws != nullptr && ws_size >= WS_NEED_BYTES) {
        scs_setup_kernel<<<NB * HW / (4 * 64), NT, 0, stream>>>(   // 1024
            d_in[0], d_in[1], d_in[3],
            (const int*)d_in[4], (const int*)d_in[5], (uint32_t*)d_ws);
        scs_main_kernel<<<16 * 4 * 16, NT, 0, stream>>>(           // 1024
            d_in[2], d_in[3], (const uint32_t*)d_ws, d_out);
    } else {
        scs_fallback_kernel<<<NB * (HW / (4 * NT)) * 4, NT, 0, stream>>>(
            d_in[0], d_in[1], d_in[2], d_in[3],
            (const int*)d_in[4], (const int*)d_in[5], d_out);
    }
}

// Round 16
// 117.225 us; speedup vs baseline: 1.0417x; 1.0417x over previous
//
#include <hip/hip_runtime.h>
#include <stdint.h>

#define NMOD 8
#define NLAY 4
#define NN   32
#define NB   16
#define HW   16384
#define BHW  262144
#define NE   256
#define NT   256

// ---- workspace layout (u32 word offsets) ----
// ex[B*HW] | in[B*HW] | pair[NE] | off[NN+1]
#define EXW 0
#define INW (NB * HW)
#define PRW (2 * NB * HW)
#define OFW (2 * NB * HW + NE)
#define WS_NEED_BYTES ((size_t)(2 * NB * HW + NE + NN + 1) * 4)

__device__ __forceinline__ float lo_bf(uint32_t u) {
    union { uint32_t u32; float f; } v; v.u32 = u << 16; return v.f;
}
__device__ __forceinline__ float hi_bf(uint32_t u) {
    union { uint32_t u32; float f; } v; v.u32 = u & 0xffff0000u; return v.f;
}
__device__ __forceinline__ uint32_t f2bf(float f) {
    union { float ff; uint32_t u; } v; v.ff = f;
    uint32_t u = v.u;
    u += 0x7fffu + ((u >> 16) & 1u);   // round-to-nearest-even
    return u >> 16;
}

// FINAL (R16) = R11 verbatim, the best-measured configuration (117.4 us).
// Structure: two-kernel split via d_ws (R6). Setup: wave-split node
// partition, coalesced 16B loads, LDS OR-combine (R9). Main: no LDS,
// scalar CSR from K$-cached ws (R10), 4-wide spill-free loops (R11),
// 2 batches x 4 dsts per block, grid 1024, bounds(256,4).
// Closed branches: wider loops spill (R3/R5/R10); aggressive launch_bounds
// spills (R12); more blocks/CU regress (R13); pair prefetch neutral (R14);
// 4bx2dst rebalance VALU-bound (R15). Spill alarm: WRITE_SIZE > ~40 MB.

// ================= setup kernel: 1024 blocks x 256 (R9 verbatim) =========
// wave w = tid>>6 handles nodes w*8..w*8+7; lane l = tid&63 -> quad
extern "C" __global__ void __launch_bounds__(NT, 4) scs_setup_kernel(
    const void* __restrict__ d_spikes,  // [N,B,H,W]  bf16 or f32
    const void* __restrict__ d_mask,    // [N,H,W]    bf16 or f32
    const void* __restrict__ d_scale,   // [2]
    const int*  __restrict__ conn_src,  // [E]
    const int*  __restrict__ conn_dst,  // [E]
    uint32_t*   __restrict__ d_ws)
{
    __shared__ uint32_t l_part[8 * NT];   // [word][wave][lane], 8 KB
    const int tid = threadIdx.x;
    const bool is_f32 = (*(const uint32_t*)d_scale) == 0x3F800000u;

    // ---- CSR build (block 0 only): group connections by dst ----
    if (blockIdx.x == 0) {
        __shared__ int s_off[NN + 1];
        __shared__ int s_cnt[NN];
        __shared__ int s_pair[NE];
        const int my_s = conn_src[tid];             // NE == NT
        const int my_d = conn_dst[tid];
        if (tid < NN) s_cnt[tid] = 0;
        __syncthreads();
        atomicAdd(&s_cnt[my_d], 1);
        __syncthreads();
        if (tid < NN) {
            int v = s_cnt[tid];
#pragma unroll
            for (int d = 1; d < NN; d <<= 1) {
                int t = __shfl_up(v, d);
                if (tid >= d) v += t;
            }
            s_off[tid + 1] = v;
            if (tid == 0) s_off[0] = 0;
            s_cnt[tid] = 0;
        }
        __syncthreads();
        {
            int pos = s_off[my_d] + atomicAdd(&s_cnt[my_d], 1);
            s_pair[pos] = (my_s << 8) | tid;
        }
        __syncthreads();
        d_ws[PRW + tid] = (uint32_t)s_pair[tid];
        if (tid <= NN) d_ws[OFW + tid] = (uint32_t)s_off[tid];
    }

    const int w   = tid >> 6;                 // wave 0..3
    const int l   = tid & 63;                 // lane = quad slot
    const int n00 = w * 8;                    // first node of this wave
    const int Q   = blockIdx.x * 64 + l;      // global quad 0..65535
    const int b   = Q >> 12;                  // HW/4 = 4096
    const int hwq = Q & (HW / 4 - 1);

    uint32_t ex0 = 0, in0 = 0, ex1 = 0, in1 = 0;
    uint32_t ex2 = 0, in2 = 0, ex3 = 0, in3 = 0;
    if (is_f32) {
        const float4* sp = (const float4*)d_spikes;
        const float4* mk = (const float4*)d_mask;
        float4 s[8], m[8];
#pragma unroll
        for (int j = 0; j < 8; ++j) {
            s[j] = sp[(n00 + j) * (BHW / 4) + b * (HW / 4) + hwq];
            m[j] = mk[(n00 + j) * (HW / 4) + hwq];
        }
#pragma unroll
        for (int j = 0; j < 8; ++j) {
            const uint32_t bit = 1u << (n00 + j);
            const float p0 = s[j].x * m[j].x;   // in {0, 1, -0.5} exactly
            const float p1 = s[j].y * m[j].y;
            const float p2 = s[j].z * m[j].z;
            const float p3 = s[j].w * m[j].w;
            if (p0 > 0.f) ex0 |= bit;  if (p0 < 0.f) in0 |= bit;
            if (p1 > 0.f) ex1 |= bit;  if (p1 < 0.f) in1 |= bit;
            if (p2 > 0.f) ex2 |= bit;  if (p2 < 0.f) in2 |= bit;
            if (p3 > 0.f) ex3 |= bit;  if (p3 < 0.f) in3 |= bit;
        }
    } else {
        const uint2* sp = (const uint2*)d_spikes;
        const uint2* mk = (const uint2*)d_mask;
        uint2 su[8], mu[8];
#pragma unroll
        for (int j = 0; j < 8; ++j) {
            su[j] = sp[(n00 + j) * (BHW / 4) + b * (HW / 4) + hwq];
            mu[j] = mk[(n00 + j) * (HW / 4) + hwq];
        }
#pragma unroll
        for (int j = 0; j < 8; ++j) {
            const uint32_t bit = 1u << (n00 + j);
            const float p0 = lo_bf(su[j].x) * lo_bf(mu[j].x);
            const float p1 = hi_bf(su[j].x) * hi_bf(mu[j].x);
            const float p2 = lo_bf(su[j].y) * lo_bf(mu[j].y);
            const float p3 = hi_bf(su[j].y) * hi_bf(mu[j].y);
            if (p0 > 0.f) ex0 |= bit;  if (p0 < 0.f) in0 |= bit;
            if (p1 > 0.f) ex1 |= bit;  if (p1 < 0.f) in1 |= bit;
            if (p2 > 0.f) ex2 |= bit;  if (p2 < 0.f) in2 |= bit;
            if (p3 > 0.f) ex3 |= bit;  if (p3 < 0.f) in3 |= bit;
        }
    }
    // partials -> LDS [word][wave][lane]; lanes hit distinct banks
    l_part[0 * NT + w * 64 + l] = ex0;  l_part[1 * NT + w * 64 + l] = ex1;
    l_part[2 * NT + w * 64 + l] = ex2;  l_part[3 * NT + w * 64 + l] = ex3;
    l_part[4 * NT + w * 64 + l] = in0;  l_part[5 * NT + w * 64 + l] = in1;
    l_part[6 * NT + w * 64 + l] = in2;  l_part[7 * NT + w * 64 + l] = in3;
    __syncthreads();
    // combine: threads 0..127; thread = (h, l): h=0 ex words, h=1 in words
    if (tid < 128) {
        const int h  = tid >> 6;        // 0 -> ex, 1 -> in
        const int ll = tid & 63;
        const int wb = h * 4;
        uint4 r;
        r.x = l_part[(wb + 0) * NT + 0 * 64 + ll] | l_part[(wb + 0) * NT + 1 * 64 + ll]
            | l_part[(wb + 0) * NT + 2 * 64 + ll] | l_part[(wb + 0) * NT + 3 * 64 + ll];
        r.y = l_part[(wb + 1) * NT + 0 * 64 + ll] | l_part[(wb + 1) * NT + 1 * 64 + ll]
            | l_part[(wb + 1) * NT + 2 * 64 + ll] | l_part[(wb + 1) * NT + 3 * 64 + ll];
        r.z = l_part[(wb + 2) * NT + 0 * 64 + ll] | l_part[(wb + 2) * NT + 1 * 64 + ll]
            | l_part[(wb + 2) * NT + 2 * 64 + ll] | l_part[(wb + 2) * NT + 3 * 64 + ll];
        r.w = l_part[(wb + 3) * NT + 0 * 64 + ll] | l_part[(wb + 3) * NT + 1 * 64 + ll]
            | l_part[(wb + 3) * NT + 2 * 64 + ll] | l_part[(wb + 3) * NT + 3 * 64 + ll];
        ((uint4*)(d_ws + (h == 0 ? EXW : INW)))[blockIdx.x * 64 + ll] = r;
    }
}

// ================= main kernel: 1024 blocks x 256, NO LDS ================
// block = (chunk 0..15, bpair 0..7, ng 0..7); 2 batches x 4 dst rows.
extern "C" __global__ void __launch_bounds__(NT, 4) scs_main_kernel(
    const void* __restrict__ d_connw,   // [E,H,W]  bf16 or f32
    const void* __restrict__ d_scale,   // [2]
    const uint32_t* __restrict__ ws,
    void* __restrict__ d_outp)          // [N,B,H,W]
{
    const int tid   = threadIdx.x;
    // XCD swizzle: idx&7 == XCD id; each XCD sees chunks {c, c+8}.
    const int idx   = blockIdx.x;                        // 0..1023
    const int chunk = (idx & 7) + 8 * ((idx >> 9) & 1);  // 0..15
    const int mid   = (idx >> 3) & 63;
    const int bp    = mid & 7;                           // 0..7
    const int ng    = mid >> 3;                          // 0..7 dst group
    const int b0    = bp * 2;
    const int b1    = b0 + 1;
    const int n0    = ng * 4;                            // 4 dsts = module ng
    const int hw0   = chunk * (4 * NT) + tid * 4;
    const int hwq   = hw0 >> 2;
    const int spqX  = (b0 * HW + hw0) >> 2;
    const int spqY  = (b1 * HW + hw0) >> 2;

    const bool is_f32 = (*(const uint32_t*)d_scale) == 0x3F800000u;

    // ---- scalar CSR bounds for this block's 4 dsts (uniform -> s_load) ----
    int off[5];
#pragma unroll
    for (int i = 0; i <= 4; ++i)
        off[i] = __builtin_amdgcn_readfirstlane((int)ws[OFW + n0 + i]);

    // ---- per-element modulated codes (vector loads) ----
    const uint4 exX = *(const uint4*)(ws + EXW + (size_t)(b0 * HW + hw0));
    const uint4 inX = *(const uint4*)(ws + INW + (size_t)(b0 * HW + hw0));
    const uint4 exY = *(const uint4*)(ws + EXW + (size_t)(b1 * HW + hw0));
    const uint4 inY = *(const uint4*)(ws + INW + (size_t)(b1 * HW + hw0));

    const uint32_t eX0 = exX.x, eX1 = exX.y, eX2 = exX.z, eX3 = exX.w;
    const uint32_t iX0 = inX.x, iX1 = inX.y, iX2 = inX.z, iX3 = inX.w;
    const uint32_t eY0 = exY.x, eY1 = exY.y, eY2 = exY.z, eY3 = exY.w;
    const uint32_t iY0 = inY.x, iY1 = inY.y, iY2 = inY.z, iY3 = inY.w;

    float w1, w2;
    if (is_f32) {
        const float* sc = (const float*)d_scale;
        w1 = sc[0]; w2 = sc[1];
    } else {
        const uint16_t* sc = (const uint16_t*)d_scale;
        w1 = lo_bf((uint32_t)sc[0]); w2 = lo_bf((uint32_t)sc[1]);
    }

    // ---- multi-scale grid from popcounts (spike bit = ex|in) ----
    float gX0, gX1, gX2, gX3, gY0, gY1, gY2, gY3;
    {
        const int m = ng;
        auto gridm = [&](uint32_t s0, uint32_t s1, uint32_t s2, uint32_t s3,
                         float& o0, float& o1, float& o2, float& o3) {
            int t0 = 0, t1 = 0, t2 = 0, t3 = 0;
            int u0 = 0, u1 = 0, u2 = 0, u3 = 0;
            if (m >= 1) {
                const int sh = 4 * (m - 1);
                t0 += __popc((s0 >> sh) & 0xFu); t1 += __popc((s1 >> sh) & 0xFu);
                t2 += __popc((s2 >> sh) & 0xFu); t3 += __popc((s3 >> sh) & 0xFu);
            }
            if (m + 1 < NMOD) {
                const int sh = 4 * (m + 1);
                t0 += __popc((s0 >> sh) & 0xFu); t1 += __popc((s1 >> sh) & 0xFu);
                t2 += __popc((s2 >> sh) & 0xFu); t3 += __popc((s3 >> sh) & 0xFu);
            }
            if (m >= 2) {
                const int sh = 4 * (m - 2);
                u0 += __popc((s0 >> sh) & 0xFu); u1 += __popc((s1 >> sh) & 0xFu);
                u2 += __popc((s2 >> sh) & 0xFu); u3 += __popc((s3 >> sh) & 0xFu);
            }
            if (m + 2 < NMOD) {
                const int sh = 4 * (m + 2);
                u0 += __popc((s0 >> sh) & 0xFu); u1 += __popc((s1 >> sh) & 0xFu);
                u2 += __popc((s2 >> sh) & 0xFu); u3 += __popc((s3 >> sh) & 0xFu);
            }
            o0 = ((float)t0 * w1 + (float)u0 * w2) * 0.25f;   // 0.25 = mean
            o1 = ((float)t1 * w1 + (float)u1 * w2) * 0.25f;
            o2 = ((float)t2 * w1 + (float)u2 * w2) * 0.25f;
            o3 = ((float)t3 * w1 + (float)u3 * w2) * 0.25f;
        };
        gridm(eX0 | iX0, eX1 | iX1, eX2 | iX2, eX3 | iX3, gX0, gX1, gX2, gX3);
        gridm(eY0 | iY0, eY1 | iY1, eY2 | iY2, eY3 | iY3, gY0, gY1, gY2, gY3);
    }

    // decode: v_e = (ex_e>>s & 1) - 0.5*(in_e>>s & 1), s in SGPR

    // ---- per-dst accumulate: 4 dst rows x 2 batches, 4-wide ONLY ----
    if (is_f32) {
        const float4* cw  = (const float4*)d_connw;
        float4*       out = (float4*)d_outp;
#pragma unroll
        for (int i = 0; i < 4; ++i) {
            const int n = n0 + i;
            float x0 = gX0, x1 = gX1, x2 = gX2, x3 = gX3;
            float y0 = gY0, y1 = gY1, y2 = gY2, y3 = gY3;
            const int beg = off[i];
            const int end = off[i + 1];
            int k = beg;
            for (; k + 4 <= end; k += 4) {
                int p[4];
#pragma unroll
                for (int j = 0; j < 4; ++j)
                    p[j] = __builtin_amdgcn_readfirstlane((int)ws[PRW + k + j]);
                float4 wv[4];
#pragma unroll
                for (int j = 0; j < 4; ++j)
                    wv[j] = cw[(p[j] & 0xff) * (HW / 4) + hwq];
#pragma unroll
                for (int j = 0; j < 4; ++j) {
                    const int s = p[j] >> 8;
                    const float vx0 = (float)((eX0 >> s) & 1u) - 0.5f * (float)((iX0 >> s) & 1u);
                    const float vx1 = (float)((eX1 >> s) & 1u) - 0.5f * (float)((iX1 >> s) & 1u);
                    const float vx2 = (float)((eX2 >> s) & 1u) - 0.5f * (float)((iX2 >> s) & 1u);
                    const float vx3 = (float)((eX3 >> s) & 1u) - 0.5f * (float)((iX3 >> s) & 1u);
                    const float vy0 = (float)((eY0 >> s) & 1u) - 0.5f * (float)((iY0 >> s) & 1u);
                    const float vy1 = (float)((eY1 >> s) & 1u) - 0.5f * (float)((iY1 >> s) & 1u);
                    const float vy2 = (float)((eY2 >> s) & 1u) - 0.5f * (float)((iY2 >> s) & 1u);
                    const float vy3 = (float)((eY3 >> s) & 1u) - 0.5f * (float)((iY3 >> s) & 1u);
                    x0 = fmaf(vx0, wv[j].x, x0);  y0 = fmaf(vy0, wv[j].x, y0);
                    x1 = fmaf(vx1, wv[j].y, x1);  y1 = fmaf(vy1, wv[j].y, y1);
                    x2 = fmaf(vx2, wv[j].z, x2);  y2 = fmaf(vy2, wv[j].z, y2);
                    x3 = fmaf(vx3, wv[j].w, x3);  y3 = fmaf(vy3, wv[j].w, y3);
                }
            }
            for (; k < end; ++k) {
                const int pk = __builtin_amdgcn_readfirstlane((int)ws[PRW + k]);
                float4 wv = cw[(pk & 0xff) * (HW / 4) + hwq];
                const int s = pk >> 8;
                const float vx0 = (float)((eX0 >> s) & 1u) - 0.5f * (float)((iX0 >> s) & 1u);
                const float vx1 = (float)((eX1 >> s) & 1u) - 0.5f * (float)((iX1 >> s) & 1u);
                const float vx2 = (float)((eX2 >> s) & 1u) - 0.5f * (float)((iX2 >> s) & 1u);
                const float vx3 = (float)((eX3 >> s) & 1u) - 0.5f * (float)((iX3 >> s) & 1u);
                const float vy0 = (float)((eY0 >> s) & 1u) - 0.5f * (float)((iY0 >> s) & 1u);
                const float vy1 = (float)((eY1 >> s) & 1u) - 0.5f * (float)((iY1 >> s) & 1u);
                const float vy2 = (float)((eY2 >> s) & 1u) - 0.5f * (float)((iY2 >> s) & 1u);
                const float vy3 = (float)((eY3 >> s) & 1u) - 0.5f * (float)((iY3 >> s) & 1u);
                x0 = fmaf(vx0, wv.x, x0);  y0 = fmaf(vy0, wv.x, y0);
                x1 = fmaf(vx1, wv.y, x1);  y1 = fmaf(vy1, wv.y, y1);
                x2 = fmaf(vx2, wv.z, x2);  y2 = fmaf(vy2, wv.z, y2);
                x3 = fmaf(vx3, wv.w, x3);  y3 = fmaf(vy3, wv.w, y3);
            }
            float4 ox; ox.x = x0; ox.y = x1; ox.z = x2; ox.w = x3;
            float4 oy; oy.x = y0; oy.y = y1; oy.z = y2; oy.w = y3;
            out[n * (BHW / 4) + spqX] = ox;
            out[n * (BHW / 4) + spqY] = oy;
        }
    } else {
        const uint2* cw  = (const uint2*)d_connw;
        uint2*       out = (uint2*)d_outp;
#pragma unroll
        for (int i = 0; i < 4; ++i) {
            const int n = n0 + i;
            float x0 = gX0, x1 = gX1, x2 = gX2, x3 = gX3;
            float y0 = gY0, y1 = gY1, y2 = gY2, y3 = gY3;
            const int beg = off[i];
            const int end = off[i + 1];
            int k = beg;
            for (; k + 4 <= end; k += 4) {
                int p[4];
#pragma unroll
                for (int j = 0; j < 4; ++j)
                    p[j] = __builtin_amdgcn_readfirstlane((int)ws[PRW + k + j]);
                uint2 wv[4];
#pragma unroll
                for (int j = 0; j < 4; ++j)
                    wv[j] = cw[(p[j] & 0xff) * (HW / 4) + hwq];
#pragma unroll
                for (int j = 0; j < 4; ++j) {
                    const int s = p[j] >> 8;
                    const float wa = lo_bf(wv[j].x), wb = hi_bf(wv[j].x);
                    const float wc = lo_bf(wv[j].y), wd = hi_bf(wv[j].y);
                    const float vx0 = (float)((eX0 >> s) & 1u) - 0.5f * (float)((iX0 >> s) & 1u);
                    const float vx1 = (float)((eX1 >> s) & 1u) - 0.5f * (float)((iX1 >> s) & 1u);
                    const float vx2 = (float)((eX2 >> s) & 1u) - 0.5f * (float)((iX2 >> s) & 1u);
                    const float vx3 = (float)((eX3 >> s) & 1u) - 0.5f * (float)((iX3 >> s) & 1u);
                    const float vy0 = (float)((eY0 >> s) & 1u) - 0.5f * (float)((iY0 >> s) & 1u);
                    const float vy1 = (float)((eY1 >> s) & 1u) - 0.5f * (float)((iY1 >> s) & 1u);
                    const float vy2 = (float)((eY2 >> s) & 1u) - 0.5f * (float)((iY2 >> s) & 1u);
                    const float vy3 = (float)((eY3 >> s) & 1u) - 0.5f * (float)((iY3 >> s) & 1u);
                    x0 = fmaf(vx0, wa, x0);  y0 = fmaf(vy0, wa, y0);
                    x1 = fmaf(vx1, wb, x1);  y1 = fmaf(vy1, wb, y1);
                    x2 = fmaf(vx2, wc, x2);  y2 = fmaf(vy2, wc, y2);
                    x3 = fmaf(vx3, wd, x3);  y3 = fmaf(vy3, wd, y3);
                }
            }
            for (; k < end; ++k) {
                const int pk = __builtin_amdgcn_readfirstlane((int)ws[PRW + k]);
                uint2 wv = cw[(pk & 0xff) * (HW / 4) + hwq];
                const int s = pk >> 8;
                const float wa = lo_bf(wv.x), wb = hi_bf(wv.x);
                const float wc = lo_bf(wv.y), wd = hi_bf(wv.y);
                const float vx0 = (float)((eX0 >> s) & 1u) - 0.5f * (float)((iX0 >> s) & 1u);
                const float vx1 = (float)((eX1 >> s) & 1u) - 0.5f * (float)((iX1 >> s) & 1u);
                const float vx2 = (float)((eX2 >> s) & 1u) - 0.5f * (float)((iX2 >> s) & 1u);
                const float vx3 = (float)((eX3 >> s) & 1u) - 0.5f * (float)((iX3 >> s) & 1u);
                const float vy0 = (float)((eY0 >> s) & 1u) - 0.5f * (float)((iY0 >> s) & 1u);
                const float vy1 = (float)((eY1 >> s) & 1u) - 0.5f * (float)((iY1 >> s) & 1u);
                const float vy2 = (float)((eY2 >> s) & 1u) - 0.5f * (float)((iY2 >> s) & 1u);
                const float vy3 = (float)((eY3 >> s) & 1u) - 0.5f * (float)((iY3 >> s) & 1u);
                x0 = fmaf(vx0, wa, x0);  y0 = fmaf(vy0, wa, y0);
                x1 = fmaf(vx1, wb, x1);  y1 = fmaf(vy1, wb, y1);
                x2 = fmaf(vx2, wc, x2);  y2 = fmaf(vy2, wc, y2);
                x3 = fmaf(vx3, wd, x3);  y3 = fmaf(vy3, wd, y3);
            }
            uint2 ox, oy;
            ox.x = f2bf(x0) | (f2bf(x1) << 16);
            ox.y = f2bf(x2) | (f2bf(x3) << 16);
            oy.x = f2bf(y0) | (f2bf(y1) << 16);
            oy.y = f2bf(y2) | (f2bf(y3) << 16);
            out[n * (BHW / 4) + spqX] = ox;
            out[n * (BHW / 4) + spqY] = oy;
        }
    }
}

// ================= fallback: R4 verbatim (ws too small) =================
struct ScsSmem {
    int off[NN + 1];
    int cnt[NN];
    int pair[NE];
};

extern "C" __global__ void __launch_bounds__(NT, 4) scs_fallback_kernel(
    const void* __restrict__ d_spikes, const void* __restrict__ d_mask,
    const void* __restrict__ d_connw,  const void* __restrict__ d_scale,
    const int*  __restrict__ conn_src, const int* __restrict__ conn_dst,
    void*       __restrict__ d_outp)
{
    __shared__ ScsSmem sm;
    const int tid   = threadIdx.x;
    const int idx   = blockIdx.x;
    const int chunk = (idx & 7) + 8 * ((idx >> 9) & 1);
    const int mid   = (idx >> 3) & 63;
    const int b     = mid & 15;
    const int ng    = mid >> 4;
    const int n0    = ng * (NN / 4);
    const int hw0   = chunk * (4 * NT) + tid * 4;
    const int hwq   = hw0 >> 2;
    const int spq   = (b * HW + hw0) >> 2;
    const bool is_f32 = (*(const uint32_t*)d_scale) == 0x3F800000u;

    const int my_s = conn_src[tid];
    const int my_d = conn_dst[tid];
    if (tid < NN) sm.cnt[tid] = 0;
    __syncthreads();
    atomicAdd(&sm.cnt[my_d], 1);
    __syncthreads();
    if (tid < NN) {
        int v = sm.cnt[tid];
#pragma unroll
        for (int d = 1; d < NN; d <<= 1) {
            int t = __shfl_up(v, d);
            if (tid >= d) v += t;
        }
        sm.off[tid + 1] = v;
        if (tid == 0) sm.off[0] = 0;
        sm.cnt[tid] = 0;
    }
    __syncthreads();
    {
        int pos = sm.off[my_d] + atomicAdd(&sm.cnt[my_d], 1);
        sm.pair[pos] = (my_s << 8) | tid;
    }

    uint32_t ex0 = 0, in0 = 0, ex1 = 0, in1 = 0;
    uint32_t ex2 = 0, in2 = 0, ex3 = 0, in3 = 0;
    float av0[NMOD], av1[NMOD], av2[NMOD], av3[NMOD];
#pragma unroll
    for (int m = 0; m < NMOD; ++m) { av0[m] = 0.f; av1[m] = 0.f; av2[m] = 0.f; av3[m] = 0.f; }

    float w1, w2;
    if (is_f32) {
        const float* sc = (const float*)d_scale;
        w1 = sc[0]; w2 = sc[1];
        const float4* sp = (const float4*)d_spikes;
        const float4* mk = (const float4*)d_mask;
#pragma unroll
        for (int g = 0; g < NN / 4; ++g) {
            float4 s[4], m[4];
#pragma unroll
            for (int j = 0; j < 4; ++j) {
                s[j] = sp[(g * 4 + j) * (BHW / 4) + spq];
                m[j] = mk[(g * 4 + j) * (HW / 4) + hwq];
            }
#pragma unroll
            for (int j = 0; j < 4; ++j) {
                const int n = g * 4 + j;
                const uint32_t bit = 1u << n;
                const float p0 = s[j].x * m[j].x;
                const float p1 = s[j].y * m[j].y;
                const float p2 = s[j].z * m[j].z;
                const float p3 = s[j].w * m[j].w;
                if (p0 > 0.f) ex0 |= bit;  if (p0 < 0.f) in0 |= bit;
                if (p1 > 0.f) ex1 |= bit;  if (p1 < 0.f) in1 |= bit;
                if (p2 > 0.f) ex2 |= bit;  if (p2 < 0.f) in2 |= bit;
                if (p3 > 0.f) ex3 |= bit;  if (p3 < 0.f) in3 |= bit;
                av0[n >> 2] += s[j].x;
                av1[n >> 2] += s[j].y;
                av2[n >> 2] += s[j].z;
                av3[n >> 2] += s[j].w;
            }
        }
    } else {
        const uint16_t* sc = (const uint16_t*)d_scale;
        w1 = lo_bf((uint32_t)sc[0]); w2 = lo_bf((uint32_t)sc[1]);
        const uint2* sp = (const uint2*)d_spikes;
        const uint2* mk = (const uint2*)d_mask;
#pragma unroll
        for (int g = 0; g < NN / 4; ++g) {
            uint2 su[4], mu[4];
#pragma unroll
            for (int j = 0; j < 4; ++j) {
                su[j] = sp[(g * 4 + j) * (BHW / 4) + spq];
                mu[j] = mk[(g * 4 + j) * (HW / 4) + hwq];
            }
#pragma unroll
            for (int j = 0; j < 4; ++j) {
                const int n = g * 4 + j;
                const uint32_t bit = 1u << n;
                const float s0 = lo_bf(su[j].x), s1 = hi_bf(su[j].x);
                const float s2 = lo_bf(su[j].y), s3 = hi_bf(su[j].y);
                const float p0 = s0 * lo_bf(mu[j].x);
                const float p1 = s1 * hi_bf(mu[j].x);
                const float p2 = s2 * lo_bf(mu[j].y);
                const float p3 = s3 * hi_bf(mu[j].y);
                if (p0 > 0.f) ex0 |= bit;  if (p0 < 0.f) in0 |= bit;
                if (p1 > 0.f) ex1 |= bit;  if (p1 < 0.f) in1 |= bit;
                if (p2 > 0.f) ex2 |= bit;  if (p2 < 0.f) in2 |= bit;
                if (p3 > 0.f) ex3 |= bit;  if (p3 < 0.f) in3 |= bit;
                av0[n >> 2] += s0;
                av1[n >> 2] += s1;
                av2[n >> 2] += s2;
                av3[n >> 2] += s3;
            }
        }
    }

    float gA0, gA1, gA2, gA3, gB0, gB1, gB2, gB3;
    {
        float g0[NMOD], g1[NMOD], g2[NMOD], g3[NMOD];
#pragma unroll
        for (int m = 0; m < NMOD; ++m) {
            float t0 = 0.f, t1 = 0.f, t2 = 0.f, t3 = 0.f;
            float u0 = 0.f, u1 = 0.f, u2 = 0.f, u3 = 0.f;
            if (m >= 1)       { t0 += av0[m-1]; t1 += av1[m-1]; t2 += av2[m-1]; t3 += av3[m-1]; }
            if (m + 1 < NMOD) { t0 += av0[m+1]; t1 += av1[m+1]; t2 += av2[m+1]; t3 += av3[m+1]; }
            if (m >= 2)       { u0 += av0[m-2]; u1 += av1[m-2]; u2 += av2[m-2]; u3 += av3[m-2]; }
            if (m + 2 < NMOD) { u0 += av0[m+2]; u1 += av1[m+2]; u2 += av2[m+2]; u3 += av3[m+2]; }
            g0[m] = (t0 * w1 + u0 * w2) * 0.25f;
            g1[m] = (t1 * w1 + u1 * w2) * 0.25f;
            g2[m] = (t2 * w1 + u2 * w2) * 0.25f;
            g3[m] = (t3 * w1 + u3 * w2) * 0.25f;
        }
        if      (ng == 0) { gA0=g0[0]; gA1=g1[0]; gA2=g2[0]; gA3=g3[0]; gB0=g0[1]; gB1=g1[1]; gB2=g2[1]; gB3=g3[1]; }
        else if (ng == 1) { gA0=g0[2]; gA1=g1[2]; gA2=g2[2]; gA3=g3[2]; gB0=g0[3]; gB1=g1[3]; gB2=g2[3]; gB3=g3[3]; }
        else if (ng == 2) { gA0=g0[4]; gA1=g1[4]; gA2=g2[4]; gA3=g3[4]; gB0=g0[5]; gB1=g1[5]; gB2=g2[5]; gB3=g3[5]; }
        else              { gA0=g0[6]; gA1=g1[6]; gA2=g2[6]; gA3=g3[6]; gB0=g0[7]; gB1=g1[7]; gB2=g2[7]; gB3=g3[7]; }
    }

    __syncthreads();

    if (is_f32) {
        const float4* cw  = (const float4*)d_connw;
        float4*       out = (float4*)d_outp;
#pragma unroll
        for (int i = 0; i < NN / 4; ++i) {
            const int n = n0 + i;
            float a0 = (i < 4) ? gA0 : gB0;
            float a1 = (i < 4) ? gA1 : gB1;
            float a2 = (i < 4) ? gA2 : gB2;
            float a3 = (i < 4) ? gA3 : gB3;
            const int beg = __builtin_amdgcn_readfirstlane(sm.off[n]);
            const int end = __builtin_amdgcn_readfirstlane(sm.off[n + 1]);
            int k = beg;
            for (; k + 4 <= end; k += 4) {
                int p[4];
#pragma unroll
                for (int j = 0; j < 4; ++j)
                    p[j] = __builtin_amdgcn_readfirstlane(sm.pair[k + j]);
                float4 wv[4];
#pragma unroll
                for (int j = 0; j < 4; ++j)
                    wv[j] = cw[(p[j] & 0xff) * (HW / 4) + hwq];
#pragma unroll
                for (int j = 0; j < 4; ++j) {
                    const int s = p[j] >> 8;
                    const float v0 = (float)((ex0 >> s) & 1u) - 0.5f * (float)((in0 >> s) & 1u);
                    const float v1 = (float)((ex1 >> s) & 1u) - 0.5f * (float)((in1 >> s) & 1u);
                    const float v2 = (float)((ex2 >> s) & 1u) - 0.5f * (float)((in2 >> s) & 1u);
                    const float v3 = (float)((ex3 >> s) & 1u) - 0.5f * (float)((in3 >> s) & 1u);
                    a0 = fmaf(v0, wv[j].x, a0);
                    a1 = fmaf(v1, wv[j].y, a1);
                    a2 = fmaf(v2, wv[j].z, a2);
                    a3 = fmaf(v3, wv[j].w, a3);
                }
            }
            for (; k < end; ++k) {
                const int pk = __builtin_amdgcn_readfirstlane(sm.pair[k]);
                float4 wv = cw[(pk & 0xff) * (HW / 4) + hwq];
                const int s = pk >> 8;
                const float v0 = (float)((ex0 >> s) & 1u) - 0.5f * (float)((in0 >> s) & 1u);
                const float v1 = (float)((ex1 >> s) & 1u) - 0.5f * (float)((in1 >> s) & 1u);
                const float v2 = (float)((ex2 >> s) & 1u) - 0.5f * (float)((in2 >> s) & 1u);
                const float v3 = (float)((ex3 >> s) & 1u) - 0.5f * (float)((in3 >> s) & 1u);
                a0 = fmaf(v0, wv.x, a0);
                a1 = fmaf(v1, wv.y, a1);
                a2 = fmaf(v2, wv.z, a2);
                a3 = fmaf(v3, wv.w, a3);
            }
            float4 o; o.x = a0; o.y = a1; o.z = a2; o.w = a3;
            out[n * (BHW / 4) + spq] = o;
        }
    } else {
        const uint2* cw  = (const uint2*)d_connw;
        uint2*       out = (uint2*)d_outp;
#pragma unroll
        for (int i = 0; i < NN / 4; ++i) {
            const int n = n0 + i;
            float a0 = (i < 4) ? gA0 : gB0;
            float a1 = (i < 4) ? gA1 : gB1;
            float a2 = (i < 4) ? gA2 : gB2;
            float a3 = (i < 4) ? gA3 : gB3;
            const int beg = __builtin_amdgcn_readfirstlane(sm.off[n]);
            const int end = __builtin_amdgcn_readfirstlane(sm.off[n + 1]);
            int k = beg;
            for (; k + 4 <= end; k += 4) {
                int p[4];
#pragma unroll
                for (int j = 0; j < 4; ++j)
                    p[j] = __builtin_amdgcn_readfirstlane(sm.pair[k + j]);
                uint2 wv[4];
#pragma unroll
                for (int j = 0; j < 4; ++j)
                    wv[j] = cw[(p[j] & 0xff) * (HW / 4) + hwq];
#pragma unroll
                for (int j = 0; j < 4; ++j) {
                    const int s = p[j] >> 8;
                    const float v0 = (float)((ex0 >> s) & 1u) - 0.5f * (float)((in0 >> s) & 1u);
                    const float v1 = (float)((ex1 >> s) & 1u) - 0.5f * (float)((in1 >> s) & 1u);
                    const float v2 = (float)((ex2 >> s) & 1u) - 0.5f * (float)((in2 >> s) & 1u);
                    const float v3 = (float)((ex3 >> s) & 1u) - 0.5f * (float)((in3 >> s) & 1u);
                    a0 = fmaf(v0, lo_bf(wv[j].x), a0);
                    a1 = fmaf(v1, hi_bf(wv[j].x), a1);
                    a2 = fmaf(v2, lo_bf(wv[j].y), a2);
                    a3 = fmaf(v3, hi_bf(wv[j].y), a3);
                }
            }
            for (; k < end; ++k) {
                const int pk = __builtin_amdgcn_readfirstlane(sm.pair[k]);
                uint2 wv = cw[(pk & 0xff) * (HW / 4) + hwq];
                const int s = pk >> 8;
                const float v0 = (float)((ex0 >> s) & 1u) - 0.5f * (float)((in0 >> s) & 1u);
                const float v1 = (float)((ex1 >> s) & 1u) - 0.5f * (float)((in1 >> s) & 1u);
                const float v2 = (float)((ex2 >> s) & 1u) - 0.5f * (float)((in2 >> s) & 1u);
                const float v3 = (float)((ex3 >> s) & 1u) - 0.5f * (float)((in3 >> s) & 1u);
                a0 = fmaf(v0, lo_bf(wv.x), a0);
                a1 = fmaf(v1, hi_bf(wv.x), a1);
                a2 = fmaf(v2, lo_bf(wv.y), a2);
                a3 = fmaf(v3, hi_bf(wv.y), a3);
            }
            uint2 o;
            o.x = f2bf(a0) | (f2bf(a1) << 16);
            o.y = f2bf(a2) | (f2bf(a3) << 16);
            out[n * (BHW / 4) + spq] = o;
        }
    }
}

extern "C" void kernel_launch(void* const* d_in, const int* in_sizes, int n_in,
                              void* d_out, int out_size, void* d_ws, size_t ws_size,
                              hipStream_t stream) {
    if (d_ws != nullptr && ws_size >= WS_NEED_BYTES) {
        scs_setup_kernel<<<NB * HW / (4 * 64), NT, 0, stream>>>(   // 1024
            d_in[0], d_in[1], d_in[3],
            (const int*)d_in[4], (const int*)d_in[5], (uint32_t*)d_ws);
        scs_main_kernel<<<16 * 8 * 8, NT, 0, stream>>>(            // 1024
            d_in[2], d_in[3], (const uint32_t*)d_ws, d_out);
    } else {
        scs_fallback_kernel<<<NB * (HW / (4 * NT)) * 4, NT, 0, stream>>>(
            d_in[0], d_in[1], d_in[2], d_in[3],
            (const int*)d_in[4], (const int*)d_in[5], d_out);
    }
}